// Round 2
// baseline (445.965 us; speedup 1.0000x reference)
//
#include <hip/hip_runtime.h>
#include <stdint.h>

// 256x256 tile, BK=64, 512 threads = 8 waves (2 M x 4 N), 8-phase schedule.
#define BM 256
#define BN 256
#define BK 64
#define TSTRIDE 32768  // f16 elems between dbuf copies (A:16384 + B:16384)

typedef _Float16 f16;
typedef __attribute__((ext_vector_type(8))) _Float16 f16x8;
typedef __attribute__((ext_vector_type(4))) _Float16 f16x4;
typedef __attribute__((ext_vector_type(4))) float floatx4;

#define SBAR() asm volatile("s_barrier" ::: "memory")
#define WAITV0() asm volatile("s_waitcnt vmcnt(0)" ::: "memory")

static __device__ __forceinline__ void async_load16(const void* g, void* l) {
    __builtin_amdgcn_global_load_lds(
        (const __attribute__((address_space(1))) unsigned int*)g,
        (__attribute__((address_space(3))) unsigned int*)l, 16, 0, 0);
}

// Stage one 64-row chunk (chunk = 0..3) of a 256x64 f16 tile into LDS.
// LDS layout: linear [256 row][8 ck][8 f16]; ck holds global chunk ck^(r&7)
// (XOR swizzle: inverse-swizzled SOURCE + linear gload_lds dest + swizzled read).
// One call = 512 threads x 16B = 8KB = rows [chunk*64, chunk*64+64).
static __device__ __forceinline__ void stage256(const f16* src, int ld, f16* lds, int tid, int chunk) {
    int c = (chunk << 9) + tid;  // 16B-chunk index within tile
    int r = c >> 3, ck = c & 7;
    const f16* gp = src + (size_t)r * ld + ((ck ^ (r & 7)) << 3);
    f16* lp = lds + (size_t)((chunk << 9) + (tid & ~63)) * 8;  // wave-uniform; HW adds lane*16B
    async_load16(gp, lp);
}

static __device__ __forceinline__ f16x8 frag256(const f16* lds, int row, int kblk) {
    // chunk (kblk ^ (row&7)) holds global k-chunk kblk of this row
    return *(const f16x8*)(lds + (((row << 3) + (kblk ^ (row & 7))) << 3));
}

// CMODE: 0 = fp32 out (+bias), 1 = f16 out (+bias), 3 = f16 transposed vT out (+bias)
template <int CMODE>
static __device__ __forceinline__ void gemm_body(
    f16* As, f16* Bs,  // As = smem, Bs = smem + 16384; dbuf stride TSTRIDE
    const f16* Ap, int lda, long long a_zoff,
    const f16* Bp, int ldb, long long b_zoff,
    void* Cp, int ldc, long long c_zoff,
    const float* bias, int K, int z)
{
    int tid = threadIdx.x;
    int lane = tid & 63;
    int wid = tid >> 6;          // 0..7
    int wm = wid >> 2, wn = wid & 3;

    // XCD-aware block swizzle (T1); all grids here have (gx*gy)%8==0.
    int gx = gridDim.x;
    int nwg = gx * gridDim.y;
    int bid = blockIdx.y * gx + blockIdx.x;
    if ((nwg & 7) == 0) {
        int chunk = nwg >> 3;
        bid = (bid & 7) * chunk + (bid >> 3);
    }
    int bx = bid % gx;
    int by = bid / gx;
    size_t row0 = (size_t)by * BM;
    size_t col0 = (size_t)bx * BN;

    floatx4 acc[8][4];
#pragma unroll
    for (int i = 0; i < 8; ++i)
#pragma unroll
        for (int j = 0; j < 4; ++j) acc[i][j] = floatx4{0.f, 0.f, 0.f, 0.f};

    const f16* a0 = Ap + (size_t)z * a_zoff + row0 * lda;
    const f16* b0 = Bp + (size_t)z * b_zoff + col0 * ldb;

    int quad = lane >> 4, mr = lane & 15;
    int NT = K >> 6;

    // Prologue: stage K-tile 0 into buffer 0, drain, barrier.
#pragma unroll
    for (int c = 0; c < 4; ++c) stage256(a0, lda, As, tid, c);
#pragma unroll
    for (int c = 0; c < 4; ++c) stage256(b0, ldb, Bs, tid, c);
    WAITV0();
    SBAR();

    for (int kt = 0; kt < NT; ++kt) {
        int cur = kt & 1;
        f16* Acur = As + cur * TSTRIDE;
        f16* Bcur = Bs + cur * TSTRIDE;
        f16* Anxt = As + (cur ^ 1) * TSTRIDE;
        f16* Bnxt = Bs + (cur ^ 1) * TSTRIDE;
        const f16* an = a0 + (size_t)(kt + 1) * BK;
        const f16* bn = b0 + (size_t)(kt + 1) * BK;
        bool pf = (kt + 1 < NT);

        // 4 phases per K-tile: phase p computes C-quadrant (mh,nh) over full BK.
        // Per phase: 12 ds_read_b128 + 2-3 gload_lds of next tile, barrier,
        // setprio(1) + 16 MFMA + setprio(0), [vmcnt(0) at p==3], barrier.
        // vmcnt never drains mid-tile: loads stay in flight across barriers (T4).
#pragma unroll
        for (int p = 0; p < 4; ++p) {
            const int mh = p >> 1, nh = p & 1;
            f16x8 af[2][4], bf[2][2];
#pragma unroll
            for (int s = 0; s < 2; ++s) {
#pragma unroll
                for (int i = 0; i < 4; ++i)
                    af[s][i] = frag256(Acur, wm * 128 + mh * 64 + i * 16 + mr, s * 4 + quad);
#pragma unroll
                for (int j = 0; j < 2; ++j)
                    bf[s][j] = frag256(Bcur, wn * 64 + nh * 32 + j * 16 + mr, s * 4 + quad);
            }
            if (pf) {
                if (p == 0) {
                    stage256(an, lda, Anxt, tid, 0);
                    stage256(an, lda, Anxt, tid, 1);
                    stage256(an, lda, Anxt, tid, 2);
                } else if (p == 1) {
                    stage256(an, lda, Anxt, tid, 3);
                    stage256(bn, ldb, Bnxt, tid, 0);
                    stage256(bn, ldb, Bnxt, tid, 1);
                } else if (p == 2) {
                    stage256(bn, ldb, Bnxt, tid, 2);
                    stage256(bn, ldb, Bnxt, tid, 3);
                }
            }
            SBAR();
            __builtin_amdgcn_s_setprio(1);
#pragma unroll
            for (int s = 0; s < 2; ++s)
#pragma unroll
                for (int j = 0; j < 2; ++j)
#pragma unroll
                    for (int i = 0; i < 4; ++i)
                        acc[mh * 4 + i][nh * 2 + j] = __builtin_amdgcn_mfma_f32_16x16x32_f16(
                            af[s][i], bf[s][j], acc[mh * 4 + i][nh * 2 + j], 0, 0, 0);
            __builtin_amdgcn_s_setprio(0);
            if (p == 3 && pf) WAITV0();  // next tile's stages: issued 2-4 phases ago
            SBAR();
        }
    }

#pragma unroll
    for (int i = 0; i < 8; ++i) {
#pragma unroll
        for (int j = 0; j < 4; ++j) {
#pragma unroll
            for (int r = 0; r < 4; ++r) {
                size_t rr = row0 + (size_t)(wm * 128 + i * 16 + quad * 4 + r);
                size_t cc = col0 + (size_t)(wn * 64 + j * 16 + mr);
                float v = acc[i][j][r];
                if (bias) v += bias[cc];
                if constexpr (CMODE == 0) {
                    float* C = (float*)Cp + (size_t)z * c_zoff;
                    C[rr * ldc + cc] = v;
                } else if constexpr (CMODE == 1) {
                    f16* C = (f16*)Cp + (size_t)z * c_zoff;
                    C[rr * ldc + cc] = (f16)v;
                } else {  // vT[b][col][s]: b = rr>>11, s = rr&2047, col dim 1024
                    f16* C = (f16*)Cp;
                    size_t b = rr >> 11, s = rr & 2047;
                    C[((b << 10) + cc) * 2048 + s] = (f16)v;
                }
            }
        }
    }
}

#define DECL_SMEM                                      \
    __shared__ __align__(16) f16 smem[2 * TSTRIDE];    \
    f16* As = smem;                                    \
    f16* Bs = smem + 16384;

// Merged q/k/v projection: z selects input tensor, weight, bias, output mode.
__global__ __launch_bounds__(512, 2) void g_qkv(const f16* x, const f16* W,
                                                f16* qk, f16* vT,
                                                const float* bq, const float* bk,
                                                const float* bv, int D, long long ten) {
    DECL_SMEM
    int z = blockIdx.z;
    const float* bias = (z == 0) ? bq : (z == 1) ? bk : bv;
    if (z < 2) {
        gemm_body<1>(As, Bs, x + (size_t)z * ten, D, 0, W + (size_t)z * D * D, D, 0,
                     qk + (size_t)z * ten, D, 0, bias, D, 0);
    } else {
        gemm_body<3>(As, Bs, x + (size_t)2 * ten, D, 0, W + (size_t)2 * D * D, D, 0,
                     vT, 0, 0, bias, D, 0);
    }
}
__global__ __launch_bounds__(512, 2) void g_scores(const f16* A, int lda, long long az,
                                                   const f16* B, int ldb, long long bz,
                                                   float* C, int ldc, long long cz, int K) {
    DECL_SMEM
    gemm_body<0>(As, Bs, A, lda, az, B, ldb, bz, C, ldc, cz, nullptr, K, blockIdx.z);
}
__global__ __launch_bounds__(512, 2) void g_attnv(const f16* A, int lda, long long az,
                                                  const f16* B, int ldb, long long bz,
                                                  f16* C, int ldc, long long cz, int K) {
    DECL_SMEM
    gemm_body<1>(As, Bs, A, lda, az, B, ldb, bz, C, ldc, cz, nullptr, K, blockIdx.z);
}
__global__ __launch_bounds__(512, 2) void g_out(const f16* A, int lda, const f16* B, int ldb,
                                                float* C, int ldc, const float* bias, int K) {
    DECL_SMEM
    gemm_body<0>(As, Bs, A, lda, 0, B, ldb, 0, C, ldc, 0, bias, K, 0);
}

// fp32 -> fp16 convert for q/k/v in one dispatch; dst = [xq|xk|xv] contiguous.
__global__ __launch_bounds__(256) void cvt_f16(const float* q, const float* k, const float* v,
                                               f16* dst, long long ten) {
    int z = blockIdx.y;
    const float* src = (z == 0) ? q : (z == 1) ? k : v;
    size_t i = ((size_t)blockIdx.x * 256 + threadIdx.x) * 4;
    float4 x = *(const float4*)(src + i);
    f16x4 h = {(f16)x.x, (f16)x.y, (f16)x.z, (f16)x.w};
    *(f16x4*)(dst + (size_t)z * ten + i) = h;
}

// All four weight transposes in one dispatch; T = [WqT|WkT|WvT|WdT] contiguous.
__global__ __launch_bounds__(256) void wtrans(const float* Wq, const float* Wk,
                                              const float* Wv, const float* Wd,
                                              f16* T, int n) {
    __shared__ float tile[32][33];
    int z = blockIdx.z;
    const float* W = (z == 0) ? Wq : (z == 1) ? Wk : (z == 2) ? Wv : Wd;
    f16* Tz = T + (size_t)z * n * n;
    int bx = blockIdx.x * 32;
    int by = blockIdx.y * 32;
    int tx = threadIdx.x & 31;
    int ty = threadIdx.x >> 5;
    for (int r = ty; r < 32; r += 8) tile[r][tx] = W[(size_t)(by + r) * n + bx + tx];
    __syncthreads();
    for (int r = ty; r < 32; r += 8) Tz[(size_t)(bx + r) * n + by + tx] = (f16)tile[tx][r];
}

// One block per row of 2048 fp32 logits; writes fp16 attn into the first half
// of the same row's storage (row byte stride stays 8192 => f16 lda 4096).
__global__ __launch_bounds__(256) void softmax_k(float* scores) {
    size_t row = blockIdx.x;
    float* rp = scores + row * 2048;
    int tid = threadIdx.x;
    int lane = tid & 63, w = tid >> 6;
    float x[8];
    float mx = -3.4e38f;
#pragma unroll
    for (int i = 0; i < 8; ++i) {
        x[i] = rp[tid + i * 256];
        mx = fmaxf(mx, x[i]);
    }
#pragma unroll
    for (int o = 32; o > 0; o >>= 1) mx = fmaxf(mx, __shfl_xor(mx, o, 64));
    __shared__ float redm[4];
    __shared__ float reds[4];
    if (lane == 0) redm[w] = mx;
    __syncthreads();  // also orders: all row reads complete before any write below
    mx = fmaxf(fmaxf(redm[0], redm[1]), fmaxf(redm[2], redm[3]));
    float s = 0.f;
#pragma unroll
    for (int i = 0; i < 8; ++i) {
        x[i] = __expf(x[i] - mx);
        s += x[i];
    }
#pragma unroll
    for (int o = 32; o > 0; o >>= 1) s += __shfl_xor(s, o, 64);
    if (lane == 0) reds[w] = s;
    __syncthreads();
    s = reds[0] + reds[1] + reds[2] + reds[3];
    float inv = 1.f / s;
    f16* op = (f16*)rp;
#pragma unroll
    for (int i = 0; i < 8; ++i) op[tid + i * 256] = (f16)(x[i] * inv);
}

extern "C" void kernel_launch(void* const* d_in, const int* in_sizes, int n_in,
                              void* d_out, int out_size, void* d_ws, size_t ws_size,
                              hipStream_t stream) {
    const float* query  = (const float*)d_in[0];
    const float* keys   = (const float*)d_in[1];
    const float* values = (const float*)d_in[2];
    const float* Wq = (const float*)d_in[3];
    const float* bq = (const float*)d_in[4];
    const float* Wk = (const float*)d_in[5];
    const float* bk = (const float*)d_in[6];
    const float* Wv = (const float*)d_in[7];
    const float* bv = (const float*)d_in[8];
    const float* Wd = (const float*)d_in[9];
    const float* bd = (const float*)d_in[10];
    float* out = (float*)d_out;

    const int S = 2048, D = 1024, NB = 4;
    const size_t TEN = (size_t)NB * S * D;  // 8.39M, TEN*2 bytes is 256-aligned

    char* p = (char*)d_ws;
    auto alloc = [&](size_t bytes) {
        char* r = p;
        p += (bytes + 255) & ~(size_t)255;
        return r;
    };
    f16* x3  = (f16*)alloc(TEN * 2 * 3);   // [xq|xk|xv]
    f16* q16 = (f16*)alloc(TEN * 2 * 2);   // [q16|k16]
    f16* k16 = q16 + TEN;
    f16* vT  = (f16*)alloc(TEN * 2);
    f16* WT  = (f16*)alloc((size_t)D * D * 2 * 4);  // [WqT|WkT|WvT|WdT]
    float* scores = (float*)p;
    long long avail = (long long)ws_size - (long long)(p - (char*)d_ws);
    long long sbytes = (long long)S * S * 4;
    int g = (avail >= 4 * sbytes) ? 4 : (avail >= 2 * sbytes) ? 2 : 1;
    f16* att = x3;  // alias: x3 is dead after the qkv projections

    dim3 blk(256);
    dim3 blk512(512);
    cvt_f16<<<dim3((unsigned)(TEN / 1024), 3), blk, 0, stream>>>(query, keys, values, x3, TEN);
    wtrans<<<dim3(D / 32, D / 32, 4), blk, 0, stream>>>(Wq, Wk, Wv, Wd, WT, D);

    g_qkv<<<dim3(D / BN, (NB * S) / BM, 3), blk512, 0, stream>>>(
        x3, WT, q16, vT, bq, bk, bv, D, (long long)TEN);

    for (int g0 = 0; g0 < NB; g0 += g) {
        int gz = (NB - g0 < g) ? (NB - g0) : g;
        dim3 sgrid(S / BN, S / BM, gz);  // (8,8,gz)
        g_scores<<<sgrid, blk512, 0, stream>>>(
            q16 + (size_t)g0 * S * D, D, (long long)S * D,
            k16 + (size_t)g0 * S * D, D, (long long)S * D,
            scores, S, (long long)S * S, D);
        softmax_k<<<dim3((unsigned)(gz * S)), blk, 0, stream>>>(scores);
        dim3 agrid(D / BN, S / BM, gz);  // (4,8,gz)
        g_attnv<<<agrid, blk512, 0, stream>>>(
            (const f16*)scores, 2 * S, (long long)S * 2 * S,
            vT + (size_t)g0 * D * S, S, (long long)D * S,
            att + (size_t)g0 * S * D, D, (long long)S * D, S);
    }

    g_out<<<dim3(D / BN, (NB * S) / BM, 1), blk512, 0, stream>>>(att, D, WT + (size_t)3 * D * D, D,
                                                                 out, D, bd, D);
}

// Round 3
// 383.671 us; speedup vs baseline: 1.1624x; 1.1624x over previous
//
#include <hip/hip_runtime.h>
#include <stdint.h>

// 256x128 tile, BK=64, 512 threads = 8 waves (4 M x 2 N), per-wave 64x64.
// Triple-buffered LDS, depth-2 prefetch, counted vmcnt(6), 1 barrier/K-tile.
#define BM 256
#define BN 128
#define BK 64
#define ATILE (BM * BK)            // 16384 f16
#define BTILE (BN * BK)            // 8192 f16
#define BUFSTRIDE (ATILE + BTILE)  // 24576 f16 per buffer; 3 bufs = 147456 B

typedef _Float16 f16;
typedef __attribute__((ext_vector_type(8))) _Float16 f16x8;
typedef __attribute__((ext_vector_type(4))) _Float16 f16x4;
typedef __attribute__((ext_vector_type(4))) float floatx4;

#define SBAR() asm volatile("s_barrier" ::: "memory")
#define WAITV6() asm volatile("s_waitcnt vmcnt(6)" ::: "memory")
#define WAITV0() asm volatile("s_waitcnt vmcnt(0)" ::: "memory")

static __device__ __forceinline__ void async_load16(const void* g, void* l) {
    __builtin_amdgcn_global_load_lds(
        (const __attribute__((address_space(1))) unsigned int*)g,
        (__attribute__((address_space(3))) unsigned int*)l, 16, 0, 0);
}

// Stage one 64-row unit (u) of a tile (rows x 64k f16) into LDS.
// LDS layout: linear [rows][8 ck][8 f16]; ck holds global chunk ck^(r&7)
// (XOR swizzle: inverse-swizzled SOURCE + linear gload_lds dest + swizzled read).
// One call = 512 threads x 16B = 8KB = rows [u*64, u*64+64).
static __device__ __forceinline__ void stage_unit(const f16* src, int ld, f16* lds, int tid, int u) {
    int c = (u << 9) + tid;  // 16B-chunk index within tile
    int r = c >> 3, ck = c & 7;
    const f16* gp = src + (size_t)r * ld + ((ck ^ (r & 7)) << 3);
    f16* lp = lds + (size_t)((u << 9) + (tid & ~63)) * 8;  // wave-uniform; HW adds lane*16B
    async_load16(gp, lp);
}

static __device__ __forceinline__ f16x8 frag(const f16* lds, int row, int kblk) {
    // chunk (kblk ^ (row&7)) holds global k-chunk kblk of this row
    return *(const f16x8*)(lds + (((row << 3) + (kblk ^ (row & 7))) << 3));
}

// CMODE: 0 = fp32 out (+bias), 1 = f16 out (+bias), 3 = f16 transposed vT out (+bias)
template <int CMODE>
static __device__ __forceinline__ void gemm_body(
    f16* smem,  // 3 * BUFSTRIDE f16
    const f16* Ap, int lda, long long a_zoff,
    const f16* Bp, int ldb, long long b_zoff,
    void* Cp, int ldc, long long c_zoff,
    const float* bias, int K, int z)
{
    int tid = threadIdx.x;
    int lane = tid & 63;
    int wid = tid >> 6;          // 0..7
    int wm = wid >> 1, wn = wid & 1;  // 4 M x 2 N

    // XCD-aware block swizzle (T1); all grids here have (gx*gy)%8==0.
    int gx = gridDim.x;
    int nwg = gx * gridDim.y;
    int bid = blockIdx.y * gx + blockIdx.x;
    if ((nwg & 7) == 0) {
        int chunk = nwg >> 3;
        bid = (bid & 7) * chunk + (bid >> 3);
    }
    int bx = bid % gx;
    int by = bid / gx;
    size_t row0 = (size_t)by * BM;
    size_t col0 = (size_t)bx * BN;

    floatx4 acc[4][4];
#pragma unroll
    for (int i = 0; i < 4; ++i)
#pragma unroll
        for (int j = 0; j < 4; ++j) acc[i][j] = floatx4{0.f, 0.f, 0.f, 0.f};

    const f16* a0 = Ap + (size_t)z * a_zoff + row0 * lda;
    const f16* b0 = Bp + (size_t)z * b_zoff + col0 * ldb;

    int quad = lane >> 4, mr = lane & 15;
    int NT = K >> 6;  // K >= 1024 here, so NT >= 16

    // Issue all 6 stage units (A:4, B:2) of K-tile kt into buffer kt%3.
    auto issue_tile = [&](int kt) {
        f16* Ab = smem + (kt % 3) * BUFSTRIDE;
        f16* Bb = Ab + ATILE;
        const f16* an = a0 + (size_t)kt * BK;
        const f16* bn = b0 + (size_t)kt * BK;
        stage_unit(an, lda, Ab, tid, 0);
        stage_unit(an, lda, Ab, tid, 1);
        stage_unit(an, lda, Ab, tid, 2);
        stage_unit(an, lda, Ab, tid, 3);
        stage_unit(bn, ldb, Bb, tid, 0);
        stage_unit(bn, ldb, Bb, tid, 1);
    };

    // Prologue: tiles 0 and 1 in flight; wait for tile 0 (6 newest stay out).
    issue_tile(0);
    issue_tile(1);
    WAITV6();
    SBAR();

    for (int kt = 0; kt < NT; ++kt) {
        f16* Ac = smem + (kt % 3) * BUFSTRIDE;
        f16* Bc = Ac + ATILE;
        if (kt + 2 < NT) issue_tile(kt + 2);  // depth-2 prefetch into buffer (kt+2)%3 = (kt-1)%3

        f16x8 af[2][4], bf[2][4];
#pragma unroll
        for (int s = 0; s < 2; ++s) {
#pragma unroll
            for (int i = 0; i < 4; ++i)
                af[s][i] = frag(Ac, wm * 64 + i * 16 + mr, s * 4 + quad);
#pragma unroll
            for (int j = 0; j < 4; ++j)
                bf[s][j] = frag(Bc, wn * 64 + j * 16 + mr, s * 4 + quad);
        }
        __builtin_amdgcn_s_setprio(1);
#pragma unroll
        for (int s = 0; s < 2; ++s)
#pragma unroll
            for (int j = 0; j < 4; ++j)
#pragma unroll
                for (int i = 0; i < 4; ++i)
                    acc[i][j] = __builtin_amdgcn_mfma_f32_16x16x32_f16(af[s][i], bf[s][j], acc[i][j], 0, 0, 0);
        __builtin_amdgcn_s_setprio(0);

        if (kt + 1 < NT) {
            // Need tile kt+1 landed (issued a full tile ago); keep tile kt+2's
            // 6 loads in flight (T4: never drain to 0 mid-loop).
            if (kt + 2 < NT) WAITV6(); else WAITV0();
            SBAR();
        }
    }

#pragma unroll
    for (int i = 0; i < 4; ++i) {
#pragma unroll
        for (int j = 0; j < 4; ++j) {
#pragma unroll
            for (int r = 0; r < 4; ++r) {
                size_t rr = row0 + (size_t)(wm * 64 + i * 16 + quad * 4 + r);
                size_t cc = col0 + (size_t)(wn * 64 + j * 16 + mr);
                float v = acc[i][j][r];
                if (bias) v += bias[cc];
                if constexpr (CMODE == 0) {
                    float* C = (float*)Cp + (size_t)z * c_zoff;
                    C[rr * ldc + cc] = v;
                } else if constexpr (CMODE == 1) {
                    f16* C = (f16*)Cp + (size_t)z * c_zoff;
                    C[rr * ldc + cc] = (f16)v;
                } else {  // vT[b][col][s]: b = rr>>11, s = rr&2047, col dim 1024
                    f16* C = (f16*)Cp;
                    size_t b = rr >> 11, s = rr & 2047;
                    C[((b << 10) + cc) * 2048 + s] = (f16)v;
                }
            }
        }
    }
}

#define DECL_SMEM __shared__ __align__(16) f16 smem[3 * BUFSTRIDE];

// Merged q/k/v projection: z selects input tensor, weight, bias, output mode.
__global__ __launch_bounds__(512, 2) void g_qkv(const f16* x, const f16* W,
                                                f16* qk, f16* vT,
                                                const float* bq, const float* bk,
                                                const float* bv, int D, long long ten) {
    DECL_SMEM
    int z = blockIdx.z;
    const float* bias = (z == 0) ? bq : (z == 1) ? bk : bv;
    if (z < 2) {
        gemm_body<1>(smem, x + (size_t)z * ten, D, 0, W + (size_t)z * D * D, D, 0,
                     qk + (size_t)z * ten, D, 0, bias, D, 0);
    } else {
        gemm_body<3>(smem, x + (size_t)2 * ten, D, 0, W + (size_t)2 * D * D, D, 0,
                     vT, 0, 0, bias, D, 0);
    }
}
__global__ __launch_bounds__(512, 2) void g_scores(const f16* A, int lda, long long az,
                                                   const f16* B, int ldb, long long bz,
                                                   float* C, int ldc, long long cz, int K) {
    DECL_SMEM
    gemm_body<0>(smem, A, lda, az, B, ldb, bz, C, ldc, cz, nullptr, K, blockIdx.z);
}
__global__ __launch_bounds__(512, 2) void g_attnv(const f16* A, int lda, long long az,
                                                  const f16* B, int ldb, long long bz,
                                                  f16* C, int ldc, long long cz, int K) {
    DECL_SMEM
    gemm_body<1>(smem, A, lda, az, B, ldb, bz, C, ldc, cz, nullptr, K, blockIdx.z);
}
__global__ __launch_bounds__(512, 2) void g_out(const f16* A, int lda, const f16* B, int ldb,
                                                float* C, int ldc, const float* bias, int K) {
    DECL_SMEM
    gemm_body<0>(smem, A, lda, 0, B, ldb, 0, C, ldc, 0, bias, K, 0);
}

// fp32 -> fp16 convert for q/k/v in one dispatch; dst = [xq|xk|xv] contiguous.
__global__ __launch_bounds__(256) void cvt_f16(const float* q, const float* k, const float* v,
                                               f16* dst, long long ten) {
    int z = blockIdx.y;
    const float* src = (z == 0) ? q : (z == 1) ? k : v;
    size_t i = ((size_t)blockIdx.x * 256 + threadIdx.x) * 4;
    float4 x = *(const float4*)(src + i);
    f16x4 h = {(f16)x.x, (f16)x.y, (f16)x.z, (f16)x.w};
    *(f16x4*)(dst + (size_t)z * ten + i) = h;
}

// All four weight transposes in one dispatch; T = [WqT|WkT|WvT|WdT] contiguous.
__global__ __launch_bounds__(256) void wtrans(const float* Wq, const float* Wk,
                                              const float* Wv, const float* Wd,
                                              f16* T, int n) {
    __shared__ float tile[32][33];
    int z = blockIdx.z;
    const float* W = (z == 0) ? Wq : (z == 1) ? Wk : (z == 2) ? Wv : Wd;
    f16* Tz = T + (size_t)z * n * n;
    int bx = blockIdx.x * 32;
    int by = blockIdx.y * 32;
    int tx = threadIdx.x & 31;
    int ty = threadIdx.x >> 5;
    for (int r = ty; r < 32; r += 8) tile[r][tx] = W[(size_t)(by + r) * n + bx + tx];
    __syncthreads();
    for (int r = ty; r < 32; r += 8) Tz[(size_t)(bx + r) * n + by + tx] = (f16)tile[tx][r];
}

// One block per row of 2048 fp32 logits; writes fp16 attn into the first half
// of the same row's storage (row byte stride stays 8192 => f16 lda 4096).
__global__ __launch_bounds__(256) void softmax_k(float* scores) {
    size_t row = blockIdx.x;
    float* rp = scores + row * 2048;
    int tid = threadIdx.x;
    int lane = tid & 63, w = tid >> 6;
    float x[8];
    float mx = -3.4e38f;
#pragma unroll
    for (int i = 0; i < 8; ++i) {
        x[i] = rp[tid + i * 256];
        mx = fmaxf(mx, x[i]);
    }
#pragma unroll
    for (int o = 32; o > 0; o >>= 1) mx = fmaxf(mx, __shfl_xor(mx, o, 64));
    __shared__ float redm[4];
    __shared__ float reds[4];
    if (lane == 0) redm[w] = mx;
    __syncthreads();  // also orders: all row reads complete before any write below
    mx = fmaxf(fmaxf(redm[0], redm[1]), fmaxf(redm[2], redm[3]));
    float s = 0.f;
#pragma unroll
    for (int i = 0; i < 8; ++i) {
        x[i] = __expf(x[i] - mx);
        s += x[i];
    }
#pragma unroll
    for (int o = 32; o > 0; o >>= 1) s += __shfl_xor(s, o, 64);
    if (lane == 0) reds[w] = s;
    __syncthreads();
    s = reds[0] + reds[1] + reds[2] + reds[3];
    float inv = 1.f / s;
    f16* op = (f16*)rp;
#pragma unroll
    for (int i = 0; i < 8; ++i) op[tid + i * 256] = (f16)(x[i] * inv);
}

extern "C" void kernel_launch(void* const* d_in, const int* in_sizes, int n_in,
                              void* d_out, int out_size, void* d_ws, size_t ws_size,
                              hipStream_t stream) {
    const float* query  = (const float*)d_in[0];
    const float* keys   = (const float*)d_in[1];
    const float* values = (const float*)d_in[2];
    const float* Wq = (const float*)d_in[3];
    const float* bq = (const float*)d_in[4];
    const float* Wk = (const float*)d_in[5];
    const float* bk = (const float*)d_in[6];
    const float* Wv = (const float*)d_in[7];
    const float* bv = (const float*)d_in[8];
    const float* Wd = (const float*)d_in[9];
    const float* bd = (const float*)d_in[10];
    float* out = (float*)d_out;

    const int S = 2048, D = 1024, NB = 4;
    const size_t TEN = (size_t)NB * S * D;  // 8.39M, TEN*2 bytes is 256-aligned

    char* p = (char*)d_ws;
    auto alloc = [&](size_t bytes) {
        char* r = p;
        p += (bytes + 255) & ~(size_t)255;
        return r;
    };
    f16* x3  = (f16*)alloc(TEN * 2 * 3);   // [xq|xk|xv]
    f16* q16 = (f16*)alloc(TEN * 2 * 2);   // [q16|k16]
    f16* k16 = q16 + TEN;
    f16* vT  = (f16*)alloc(TEN * 2);
    f16* WT  = (f16*)alloc((size_t)D * D * 2 * 4);  // [WqT|WkT|WvT|WdT]
    float* scores = (float*)p;
    long long avail = (long long)ws_size - (long long)(p - (char*)d_ws);
    long long sbytes = (long long)S * S * 4;
    int g = (avail >= 4 * sbytes) ? 4 : (avail >= 2 * sbytes) ? 2 : 1;
    f16* att = x3;  // alias: x3 is dead after the qkv projections

    dim3 blk(256);
    dim3 blk512(512);
    cvt_f16<<<dim3((unsigned)(TEN / 1024), 3), blk, 0, stream>>>(query, keys, values, x3, TEN);
    wtrans<<<dim3(D / 32, D / 32, 4), blk, 0, stream>>>(Wq, Wk, Wv, Wd, WT, D);

    g_qkv<<<dim3(D / BN, (NB * S) / BM, 3), blk512, 0, stream>>>(
        x3, WT, q16, vT, bq, bk, bv, D, (long long)TEN);

    for (int g0 = 0; g0 < NB; g0 += g) {
        int gz = (NB - g0 < g) ? (NB - g0) : g;
        dim3 sgrid(S / BN, S / BM, gz);  // (16,8,gz)
        g_scores<<<sgrid, blk512, 0, stream>>>(
            q16 + (size_t)g0 * S * D, D, (long long)S * D,
            k16 + (size_t)g0 * S * D, D, (long long)S * D,
            scores, S, (long long)S * S, D);
        softmax_k<<<dim3((unsigned)(gz * S)), blk, 0, stream>>>(scores);
        dim3 agrid(D / BN, S / BM, gz);  // (8,8,gz)
        g_attnv<<<agrid, blk512, 0, stream>>>(
            (const f16*)scores, 2 * S, (long long)S * 2 * S,
            vT + (size_t)g0 * D * S, S, (long long)D * S,
            att + (size_t)g0 * S * D, D, (long long)S * D, S);
    }

    g_out<<<dim3(D / BN, (NB * S) / BM, 1), blk512, 0, stream>>>(att, D, WT + (size_t)3 * D * D, D,
                                                                 out, D, bd, D);
}